// Round 1
// 436.370 us; speedup vs baseline: 1.5473x; 1.5473x over previous
//
#include <hip/hip_runtime.h>
#include <hip/hip_bf16.h>

typedef __attribute__((ext_vector_type(8))) short bf16x8;
typedef __attribute__((ext_vector_type(4))) float floatx4;
typedef __attribute__((ext_vector_type(4))) short short4v;

__device__ inline short f2bf(float f) {
  union { float f; unsigned u; } v; v.f = f;
  unsigned r = v.u + 0x7fffu + ((v.u >> 16) & 1u);  // round-to-nearest-even
  return (short)(r >> 16);
}

__device__ inline void gload_lds16(const short* g, short* l) {
  __builtin_amdgcn_global_load_lds(
      (const __attribute__((address_space(1))) unsigned int*)g,
      (__attribute__((address_space(3))) unsigned int*)l, 16, 0, 0);
}

// ---------------- Kernel 0: fp32 -> bf16 conversion (x and the 3 weight mats)
__global__ __launch_bounds__(256) void cvt_kernel(
    const float* __restrict__ x, const float* __restrict__ wq,
    const float* __restrict__ wk, const float* __restrict__ wv,
    short* __restrict__ Xb, short* __restrict__ Wb) {
  long i4 = (long)(blockIdx.x * 256 + threadIdx.x) * 4;
  const float* src; short* dst; long off;
  if (i4 < 16777216L) {
    src = x; dst = Xb; off = i4;
  } else {
    long j = i4 - 16777216L;
    int mat = (int)(j >> 20);
    src = (mat == 0) ? wq : ((mat == 1) ? wk : wv);
    dst = Wb + ((long)mat << 20);
    off = j & 1048575L;
  }
  float4 v = *(const float4*)(src + off);
  short4v o; o.x = f2bf(v.x); o.y = f2bf(v.y); o.z = f2bf(v.z); o.w = f2bf(v.w);
  *(short4v*)(dst + off) = o;
}

// ---------------- Kernel 1: QKV NT-GEMM (m97 structure), epilogue writes
// Q/K/V in MFMA-FRAGMENT-LINEAR layouts so flash_attn's loads are lane*8-coalesced:
//  Qf/Kf: [b][t16 (t>>4)][dc (d>>5)][lane=((d>>3)&3)*16 + (t&15)][j=d&7]
//  Vf   : [b][c16 (c>>4)][kc (t>>5)][lane=((t>>3)&3)*16 + (c&15)][j=t&7]
__global__ __launch_bounds__(256) void qkv_gemm(
    const short* __restrict__ Xb, const short* __restrict__ Wb,
    const float* __restrict__ bq, const float* __restrict__ bk,
    const float* __restrict__ bv,
    short* __restrict__ Qf, short* __restrict__ Kf, short* __restrict__ Vf) {
  __shared__ short As[128 * 32];
  __shared__ short Bs[128 * 32];

  const int tid  = threadIdx.x;
  const int wave = tid >> 6, lane = tid & 63;
  const int quad = lane >> 4, l16 = lane & 15;
  const int wm = wave & 1, wn = wave >> 1;

  const int row0 = blockIdx.x * 128;
  const int col0 = blockIdx.y * 128;

  const int srow = wave * 16 + (lane >> 2);
  const int skof = (lane & 3) * 8;
  const short* gA0 = Xb + (size_t)(row0 + srow) * 1024 + skof;
  const short* gA1 = gA0 + (size_t)64 * 1024;
  const short* gB0 = Wb + (size_t)(col0 + srow) * 1024 + skof;
  const short* gB1 = gB0 + (size_t)64 * 1024;
  short* lA0 = As + (wave * 16) * 32 + lane * 8;
  short* lA1 = As + (64 + wave * 16) * 32 + lane * 8;
  short* lB0 = Bs + (wave * 16) * 32 + lane * 8;
  short* lB1 = Bs + (64 + wave * 16) * 32 + lane * 8;

  floatx4 acc[4][4] = {};

  for (int k = 0; k < 1024; k += 32) {
    gload_lds16(gA0 + k, lA0);
    gload_lds16(gA1 + k, lA1);
    gload_lds16(gB0 + k, lB0);
    gload_lds16(gB1 + k, lB1);
    __syncthreads();

    bf16x8 af[4], bfr[4];
#pragma unroll
    for (int mt = 0; mt < 4; mt++)
      af[mt] = *(const bf16x8*)(As + (wm * 64 + mt * 16 + l16) * 32 + quad * 8);
#pragma unroll
    for (int nb = 0; nb < 4; nb++)
      bfr[nb] = *(const bf16x8*)(Bs + (wn * 64 + nb * 16 + l16) * 32 + quad * 8);
#pragma unroll
    for (int mt = 0; mt < 4; mt++)
#pragma unroll
      for (int nb = 0; nb < 4; nb++)
        acc[mt][nb] = __builtin_amdgcn_mfma_f32_16x16x32_bf16(af[mt], bfr[nb], acc[mt][nb], 0, 0, 0);
    __syncthreads();
  }

#pragma unroll
  for (int nb = 0; nb < 4; nb++) {
    const int col = col0 + wn * 64 + nb * 16 + l16;
    const int mat = col >> 10;
    const int cn  = col & 1023;
    const float* bias = (mat == 0) ? bq : (mat == 1) ? bk : bv;
    const float bb = bias[cn];
    const float qs = (mat == 0) ? 0.03125f : 1.0f;  // fold 1/sqrt(C) into Q
#pragma unroll
    for (int mt = 0; mt < 4; mt++) {
#pragma unroll
      for (int r = 0; r < 4; r++) {
        const int row = row0 + wm * 64 + mt * 16 + quad * 4 + r;
        short o = f2bf((acc[mt][nb][r] + bb) * qs);
        const int bat = row >> 11, t = row & 2047;
        if (mat <= 1) {
          // Q/K fragment-linear: m = t, k = cn(=d)
          const size_t idx = ((((size_t)bat * 128 + (t >> 4)) * 32 + (cn >> 5)) << 9)
                           + ((((cn >> 3) & 3) * 16 + (t & 15)) << 3) + (cn & 7);
          if (mat == 0) Qf[idx] = o; else Kf[idx] = o;
        } else {
          // V fragment-linear (PV B-operand): n = cn(=c), k = t(=kv)
          const size_t idx = ((((size_t)bat * 64 + (cn >> 4)) * 64 + (t >> 5)) << 9)
                           + ((((t >> 3) & 3) * 16 + (cn & 15)) << 3) + (t & 7);
          Vf[idx] = o;
        }
      }
    }
  }
}

// ---------------- Kernel 2: flash attention, causal.
// Block = 512 thr (8 waves). QBLK = 32 q-rows, KV-tile = 64.
// QK^T: wave w owns d in [w*128, w*128+128); partial S summed across waves in LDS.
// PV:   wave w owns V cols [w*128, w*128+128).
// Load balance: block handles the q-tile PAIR (63-p, p) -> exactly 33 kv-tile
// iterations per block, grid = 8 batches x 32 pairs = 256 blocks = 1/CU.
// batch = blockIdx&7 keeps each batch's K/V on one XCD's L2.
__global__ __launch_bounds__(512, 2) void flash_attn(
    const short* __restrict__ Qf, const short* __restrict__ Kf,
    const short* __restrict__ Vf, float* __restrict__ out) {
  __shared__ float Sf[8][32][68];   // +4 pad: 2-way-max banks on partial stores
  __shared__ short Pb[32][72];
  __shared__ float arow[32];
  __shared__ float lrow[32];

  const int b   = blockIdx.x & 7;
  const int p   = blockIdx.x >> 3;          // 0..31
  const int tid = threadIdx.x;
  const int wave = tid >> 6, lane = tid & 63;
  const int quad = lane >> 4, l16 = lane & 15;
  const int row = tid >> 4, sub = tid & 15; // softmax: 32 rows x 16 threads (same wave)

#pragma unroll 1
  for (int pass = 0; pass < 2; ++pass) {
    const int j = pass ? p : (63 - p);      // heavy tile first (cross-block kv sync)
    const int ntiles = (j >> 1) + 1;
    const int gr = j * 32 + row;

    // Q fragments: 32 rows x this wave's 128 d, loaded once (coalesced)
    bf16x8 qfr[2][4];
#pragma unroll
    for (int mt = 0; mt < 2; mt++) {
      const short* qp = Qf + ((((size_t)b * 128 + j * 2 + mt) * 32 + wave * 4) << 9) + lane * 8;
#pragma unroll
      for (int dc = 0; dc < 4; dc++)
        qfr[mt][dc] = *(const bf16x8*)(qp + ((size_t)dc << 9));
    }

    floatx4 O[2][8] = {};
    float m_i = -1e30f, l_i = 0.0f;

    for (int kt = 0; kt < ntiles; kt++) {
      // ---- partial S over this wave's 128 d, all 64 kv cols
      const short* kp = Kf + ((((size_t)b * 128 + kt * 4) * 32 + wave * 4) << 9) + lane * 8;
      bf16x8 kb[4][4];
#pragma unroll
      for (int nt = 0; nt < 4; nt++)
#pragma unroll
        for (int dc = 0; dc < 4; dc++)
          kb[nt][dc] = *(const bf16x8*)(kp + (((size_t)nt * 32 + dc) << 9));

      floatx4 s[2][4] = {};
#pragma unroll
      for (int nt = 0; nt < 4; nt++)
#pragma unroll
        for (int dc = 0; dc < 4; dc++)
#pragma unroll
          for (int mt = 0; mt < 2; mt++)
            s[mt][nt] = __builtin_amdgcn_mfma_f32_16x16x32_bf16(qfr[mt][dc], kb[nt][dc], s[mt][nt], 0, 0, 0);

#pragma unroll
      for (int mt = 0; mt < 2; mt++)
#pragma unroll
        for (int nt = 0; nt < 4; nt++)
#pragma unroll
          for (int r = 0; r < 4; r++)
            Sf[wave][mt * 16 + quad * 4 + r][nt * 16 + l16] = s[mt][nt][r];
      __syncthreads();  // B0: all partials in LDS

      // ---- issue V loads now; they stream under the softmax VALU work
      const short* vp = Vf + ((((size_t)b * 64 + wave * 8) * 64 + kt * 2) << 9) + lane * 8;
      bf16x8 vb[2][8];
#pragma unroll
      for (int nb = 0; nb < 8; nb++)
#pragma unroll
        for (int kc = 0; kc < 2; kc++)
          vb[kc][nb] = *(const bf16x8*)(vp + (((size_t)nb * 64 + kc) << 9));

      // ---- online softmax (sum 8 partials, register m/l, 16-lane shuffle reduce)
      const int kvbase = kt * 64;
      floatx4 vsum = {};
#pragma unroll
      for (int w = 0; w < 8; w++)
        vsum += *(const floatx4*)&Sf[w][row][sub * 4];
      float sv[4], mx = -1e30f;
#pragma unroll
      for (int jj = 0; jj < 4; jj++) {
        float v = vsum[jj];
        if (kvbase + sub * 4 + jj > gr) v = -1e30f;  // causal mask
        sv[jj] = v;
        mx = fmaxf(mx, v);
      }
#pragma unroll
      for (int msk = 1; msk <= 8; msk <<= 1)
        mx = fmaxf(mx, __shfl_xor(mx, msk, 64));
      const float mn = fmaxf(m_i, mx);
      const float alpha = __expf(m_i - mn);
      m_i = mn;
      float ps = 0.0f;
      short4v pb4;
#pragma unroll
      for (int jj = 0; jj < 4; jj++) {
        float pe = __expf(sv[jj] - mn);
        ps += pe;
        pb4[jj] = f2bf(pe);
      }
      *(short4v*)&Pb[row][sub * 4] = pb4;
#pragma unroll
      for (int msk = 1; msk <= 8; msk <<= 1)
        ps += __shfl_xor(ps, msk, 64);
      l_i = l_i * alpha + ps;
      if (sub == 0) arow[row] = alpha;
      __syncthreads();  // B1: Pb + arow ready (drains vb loads too)

      // ---- O = diag(alpha) O + P V  (wave owns 128 V cols)
      float al[2][4];
#pragma unroll
      for (int mt = 0; mt < 2; mt++)
#pragma unroll
        for (int r = 0; r < 4; r++) al[mt][r] = arow[mt * 16 + quad * 4 + r];
#pragma unroll
      for (int mt = 0; mt < 2; mt++)
#pragma unroll
        for (int nb = 0; nb < 8; nb++)
#pragma unroll
          for (int r = 0; r < 4; r++) O[mt][nb][r] *= al[mt][r];

#pragma unroll
      for (int kc = 0; kc < 2; kc++)
#pragma unroll
        for (int mt = 0; mt < 2; mt++) {
          bf16x8 pa = *(const bf16x8*)&Pb[mt * 16 + l16][kc * 32 + quad * 8];
#pragma unroll
          for (int nb = 0; nb < 8; nb++)
            O[mt][nb] = __builtin_amdgcn_mfma_f32_16x16x32_bf16(pa, vb[kc][nb], O[mt][nb], 0, 0, 0);
        }
    }  // kt

    // ---- epilogue for this q-tile
    if (sub == 0) lrow[row] = 1.0f / l_i;
    __syncthreads();
    float linv[2][4];
#pragma unroll
    for (int mt = 0; mt < 2; mt++)
#pragma unroll
      for (int r = 0; r < 4; r++) linv[mt][r] = lrow[mt * 16 + quad * 4 + r];
#pragma unroll
    for (int mt = 0; mt < 2; mt++)
#pragma unroll
      for (int nb = 0; nb < 8; nb++)
#pragma unroll
        for (int r = 0; r < 4; r++) {
          const int rr = j * 32 + mt * 16 + quad * 4 + r;
          const int cc = wave * 128 + nb * 16 + l16;
          out[((size_t)b * 2048 + rr) * 1024 + cc] = O[mt][nb][r] * linv[mt][r];
        }
  }  // pass
}

extern "C" void kernel_launch(void* const* d_in, const int* in_sizes, int n_in,
                              void* d_out, int out_size, void* d_ws, size_t ws_size,
                              hipStream_t stream) {
  const float* x  = (const float*)d_in[0];
  const float* Wq = (const float*)d_in[1];
  const float* bq = (const float*)d_in[2];
  const float* Wk = (const float*)d_in[3];
  const float* bk = (const float*)d_in[4];
  const float* Wv = (const float*)d_in[5];
  const float* bv = (const float*)d_in[6];
  float* out = (float*)d_out;

  char* ws = (char*)d_ws;
  short* Xb = (short*)(ws);                 // 16384x1024 bf16 = 33,554,432 B
  short* Wb = (short*)(ws + 33554432);      // 3x1024x1024 bf16 = 6,291,456 B
  short* Qf = (short*)(ws + 39845888);      // 33,554,432 B fragment-linear (pre-scaled 1/32)
  short* Kf = (short*)(ws + 73400320);      // 33,554,432 B fragment-linear
  short* Vf = (short*)(ws + 106954752);     // 33,554,432 B fragment-linear

  cvt_kernel<<<19456, 256, 0, stream>>>(x, Wq, Wk, Wv, Xb, Wb);
  qkv_gemm<<<dim3(128, 24), 256, 0, stream>>>(Xb, Wb, bq, bk, bv, Qf, Kf, Vf);
  flash_attn<<<256, 512, 0, stream>>>(Qf, Kf, Vf, out);
}

// Round 2
// 386.069 us; speedup vs baseline: 1.7489x; 1.1303x over previous
//
#include <hip/hip_runtime.h>
#include <hip/hip_bf16.h>

typedef __attribute__((ext_vector_type(8))) short bf16x8;
typedef __attribute__((ext_vector_type(4))) float floatx4;
typedef __attribute__((ext_vector_type(4))) short short4v;

__device__ inline short f2bf(float f) {
  union { float f; unsigned u; } v; v.f = f;
  unsigned r = v.u + 0x7fffu + ((v.u >> 16) & 1u);  // round-to-nearest-even
  return (short)(r >> 16);
}

__device__ inline void gload_lds16(const short* g, short* l) {
  __builtin_amdgcn_global_load_lds(
      (const __attribute__((address_space(1))) unsigned int*)g,
      (__attribute__((address_space(3))) unsigned int*)l, 16, 0, 0);
}

// ---------------- Kernel 0: fp32 -> bf16 conversion (x and the 3 weight mats)
__global__ __launch_bounds__(256) void cvt_kernel(
    const float* __restrict__ x, const float* __restrict__ wq,
    const float* __restrict__ wk, const float* __restrict__ wv,
    short* __restrict__ Xb, short* __restrict__ Wb) {
  long i4 = (long)(blockIdx.x * 256 + threadIdx.x) * 4;
  const float* src; short* dst; long off;
  if (i4 < 16777216L) {
    src = x; dst = Xb; off = i4;
  } else {
    long j = i4 - 16777216L;
    int mat = (int)(j >> 20);
    src = (mat == 0) ? wq : ((mat == 1) ? wk : wv);
    dst = Wb + ((long)mat << 20);
    off = j & 1048575L;
  }
  float4 v = *(const float4*)(src + off);
  short4v o; o.x = f2bf(v.x); o.y = f2bf(v.y); o.z = f2bf(v.z); o.w = f2bf(v.w);
  *(short4v*)(dst + off) = o;
}

// ---------------- Kernel 1: QKV NT-GEMM, 256x256 tile, 8-phase pipelined.
// 512 thr = 8 waves (2M x 4N). K split in 32-wide slabs; 4-slot LDS ring per
// operand (256 rows x 32 k x bf16 = 16KB/slot, 64KB/operand, 128KB total).
// Per k-step: 2 phases of 16 MFMA; stage 1 slab/phase (2 x global_load_lds,
// slab s+3 -> slot (s-1)&3, freed one barrier earlier). Counted vmcnt(4) once
// per K-tile (never 0) keeps 2-3 slabs in flight across barriers (T3+T4).
// LDS XOR swizzle: k-slot ^= (row>>1)&3 -> ds_read_b128 ~2-way (free) (T2).
// setprio around MFMA clusters (T5); bijective XCD swizzle, A-panel-major (T1).
// Epilogue writes the SAME fragment-linear Qf/Kf/Vf layouts as before:
//  Qf/Kf: [b][t>>4][d>>5][((d>>3)&3)*16 + (t&15)][d&7]
//  Vf   : [b][c>>4][t>>5][((t>>3)&3)*16 + (c&15)][t&7]
__global__ __launch_bounds__(512, 2) void qkv_gemm(
    const short* __restrict__ Xb, const short* __restrict__ Wb,
    const float* __restrict__ bq, const float* __restrict__ bk,
    const float* __restrict__ bv,
    short* __restrict__ Qf, short* __restrict__ Kf, short* __restrict__ Vf) {
  __shared__ short As[4 * 8192];   // 4-slot ring, 256x32 bf16 each, swizzled
  __shared__ short Bs[4 * 8192];

  const int tid  = threadIdx.x;
  const int wave = tid >> 6, lane = tid & 63;
  const int quad = lane >> 4, l16 = lane & 15;
  const int wm = wave >> 2, wn = wave & 3;

  int bid = (int)blockIdx.x;
  bid = (bid & 7) * 96 + (bid >> 3);          // XCD swizzle (768 % 8 == 0)
  const int bx = bid / 12, by = bid % 12;     // A-panel-major within XCD chunk
  const int row0 = bx * 256, colbase = by * 256;

  // ---- staging addresses (global source pre-XOR'd so linear LDS dest + XOR'd
  // read form the same involution; rule 21)
  const int sr = tid >> 2;                              // row 0..127 per round
  const int sx = (((tid & 3) ^ ((tid >> 3) & 3)) << 3); // swizzled k-elem off
  const short* gAbase = Xb + (size_t)(row0 + sr) * 1024 + sx;
  const short* gBbase = Wb + (size_t)(colbase + sr) * 1024 + sx;
  short* lA = (short*)As + tid * 8;
  short* lB = (short*)Bs + tid * 8;

#define STAGE_A(S) { const int _s = (S); const int _sl = (_s & 3) * 8192; \
  gload_lds16(gAbase + (size_t)_s * 32, lA + _sl); \
  gload_lds16(gAbase + (size_t)_s * 32 + 131072, lA + _sl + 4096); }
#define STAGE_B(S) { const int _s = (S); const int _sl = (_s & 3) * 8192; \
  gload_lds16(gBbase + (size_t)_s * 32, lB + _sl); \
  gload_lds16(gBbase + (size_t)_s * 32 + 131072, lB + _sl + 4096); }

  // ---- fragment read offsets (shorts), swizzled
  const int coff = (quad ^ ((l16 >> 1) & 3)) * 8;
  const int aRow = (wm * 128 + l16) * 32 + coff;
  const int bRow = (wn * 64 + l16) * 32 + coff;

  floatx4 acc[8][4] = {};

  // ---- prologue: stage slabs 0,1,2; wait with slab2 still in flight
  STAGE_A(0) STAGE_B(0) STAGE_A(1) STAGE_B(1) STAGE_A(2) STAGE_B(2)
  asm volatile("s_waitcnt vmcnt(4)" ::: "memory");
  __builtin_amdgcn_s_barrier();

#define PHASE_BAR() do { __builtin_amdgcn_sched_barrier(0); \
                         __builtin_amdgcn_s_barrier(); } while (0)
#define MFMA_ROW(MT, AF) \
  acc[MT][0] = __builtin_amdgcn_mfma_f32_16x16x32_bf16(AF, bf0, acc[MT][0], 0, 0, 0); \
  acc[MT][1] = __builtin_amdgcn_mfma_f32_16x16x32_bf16(AF, bf1, acc[MT][1], 0, 0, 0); \
  acc[MT][2] = __builtin_amdgcn_mfma_f32_16x16x32_bf16(AF, bf2, acc[MT][2], 0, 0, 0); \
  acc[MT][3] = __builtin_amdgcn_mfma_f32_16x16x32_bf16(AF, bf3, acc[MT][3], 0, 0, 0);

#define STEP(S, WAIT) { \
  const int sl_ = ((S) & 3) * 8192; \
  /* phase h=0: 8 ds_read_b128, stage A(s+3), 16 MFMA */ \
  bf16x8 af0 = *(const bf16x8*)(As + sl_ + aRow); \
  bf16x8 af1 = *(const bf16x8*)(As + sl_ + aRow + 512); \
  bf16x8 af2 = *(const bf16x8*)(As + sl_ + aRow + 1024); \
  bf16x8 af3 = *(const bf16x8*)(As + sl_ + aRow + 1536); \
  bf16x8 bf0 = *(const bf16x8*)(Bs + sl_ + bRow); \
  bf16x8 bf1 = *(const bf16x8*)(Bs + sl_ + bRow + 512); \
  bf16x8 bf2 = *(const bf16x8*)(Bs + sl_ + bRow + 1024); \
  bf16x8 bf3 = *(const bf16x8*)(Bs + sl_ + bRow + 1536); \
  STAGE_A(((S) + 3) & 31) \
  PHASE_BAR(); \
  __builtin_amdgcn_s_setprio(1); \
  MFMA_ROW(0, af0) MFMA_ROW(1, af1) MFMA_ROW(2, af2) MFMA_ROW(3, af3) \
  __builtin_amdgcn_s_setprio(0); \
  PHASE_BAR(); \
  /* phase h=1: 4 ds_read_b128 (B reused in regs), stage B(s+3), 16 MFMA */ \
  bf16x8 ag0 = *(const bf16x8*)(As + sl_ + aRow + 2048); \
  bf16x8 ag1 = *(const bf16x8*)(As + sl_ + aRow + 2560); \
  bf16x8 ag2 = *(const bf16x8*)(As + sl_ + aRow + 3072); \
  bf16x8 ag3 = *(const bf16x8*)(As + sl_ + aRow + 3584); \
  STAGE_B(((S) + 3) & 31) \
  PHASE_BAR(); \
  __builtin_amdgcn_s_setprio(1); \
  MFMA_ROW(4, ag0) MFMA_ROW(5, ag1) MFMA_ROW(6, ag2) MFMA_ROW(7, ag3) \
  __builtin_amdgcn_s_setprio(0); \
  if (WAIT) { asm volatile("s_waitcnt vmcnt(4)" ::: "memory"); } \
  PHASE_BAR(); \
}

#pragma unroll 1
  for (int kt = 0; kt < 16; ++kt) {
    STEP(kt * 2, 0)
    STEP(kt * 2 + 1, 1)
  }

  // ---- epilogue: bias + (Q-only) 1/sqrt(C) scale, fragment-linear scatter
  const int mat = by >> 2;                    // block-uniform (256 | 1024)
  const float* bias = (mat == 0) ? bq : (mat == 1) ? bk : bv;
  const float qs = (mat == 0) ? 0.03125f : 1.0f;
  int cn[4]; float bb[4];
#pragma unroll
  for (int nb = 0; nb < 4; ++nb) {
    cn[nb] = ((by & 3) << 8) + wn * 64 + nb * 16 + l16;
    bb[nb] = bias[cn[nb]];
  }

  if (mat <= 1) {
    short* dst = (mat == 0) ? Qf : Kf;
#pragma unroll
    for (int mt = 0; mt < 8; ++mt) {
      const int rowb = row0 + wm * 128 + mt * 16 + quad * 4;
      const int bat = rowb >> 11, t0 = rowb & 2047;
#pragma unroll
      for (int nb = 0; nb < 4; ++nb) {
        const int c = cn[nb];
        const size_t base = ((((size_t)bat * 128 + (t0 >> 4)) * 32 + (c >> 5)) << 9)
                          + ((((c >> 3) & 3) * 16 + (t0 & 15)) << 3) + (c & 7);
#pragma unroll
        for (int r = 0; r < 4; ++r)
          dst[base + (size_t)r * 8] = f2bf((acc[mt][nb][r] + bb[nb]) * qs);
      }
    }
  } else {
#pragma unroll
    for (int mt = 0; mt < 8; ++mt) {
      const int rowb = row0 + wm * 128 + mt * 16 + quad * 4;
      const int bat = rowb >> 11, t0 = rowb & 2047;
#pragma unroll
      for (int nb = 0; nb < 4; ++nb) {
        const int c = cn[nb];
        const size_t base = ((((size_t)bat * 64 + (c >> 4)) * 64 + (t0 >> 5)) << 9)
                          + ((((t0 >> 3) & 3) * 16 + (c & 15)) << 3) + (t0 & 7);
        short4v ov;
#pragma unroll
        for (int r = 0; r < 4; ++r) ov[r] = f2bf(acc[mt][nb][r] + bb[nb]);
        *(short4v*)(Vf + base) = ov;   // 4 consecutive t -> 8B vector store
      }
    }
  }
#undef STEP
#undef MFMA_ROW
#undef PHASE_BAR
#undef STAGE_A
#undef STAGE_B
}

// ---------------- Kernel 2: flash attention, causal.
// Block = 512 thr (8 waves). QBLK = 32 q-rows, KV-tile = 64.
// QK^T: wave w owns d in [w*128, w*128+128); partial S summed across waves in LDS.
// PV:   wave w owns V cols [w*128, w*128+128).
// Load balance: block handles the q-tile PAIR (63-p, p) -> exactly 33 kv-tile
// iterations per block, grid = 8 batches x 32 pairs = 256 blocks = 1/CU.
__global__ __launch_bounds__(512, 2) void flash_attn(
    const short* __restrict__ Qf, const short* __restrict__ Kf,
    const short* __restrict__ Vf, float* __restrict__ out) {
  __shared__ float Sf[8][32][68];
  __shared__ short Pb[32][72];
  __shared__ float arow[32];
  __shared__ float lrow[32];

  const int b   = blockIdx.x & 7;
  const int p   = blockIdx.x >> 3;          // 0..31
  const int tid = threadIdx.x;
  const int wave = tid >> 6, lane = tid & 63;
  const int quad = lane >> 4, l16 = lane & 15;
  const int row = tid >> 4, sub = tid & 15; // softmax: 32 rows x 16 threads

#pragma unroll 1
  for (int pass = 0; pass < 2; ++pass) {
    const int j = pass ? p : (63 - p);      // heavy tile first
    const int ntiles = (j >> 1) + 1;
    const int gr = j * 32 + row;

    bf16x8 qfr[2][4];
#pragma unroll
    for (int mt = 0; mt < 2; mt++) {
      const short* qp = Qf + ((((size_t)b * 128 + j * 2 + mt) * 32 + wave * 4) << 9) + lane * 8;
#pragma unroll
      for (int dc = 0; dc < 4; dc++)
        qfr[mt][dc] = *(const bf16x8*)(qp + ((size_t)dc << 9));
    }

    floatx4 O[2][8] = {};
    float m_i = -1e30f, l_i = 0.0f;

    for (int kt = 0; kt < ntiles; kt++) {
      const short* kp = Kf + ((((size_t)b * 128 + kt * 4) * 32 + wave * 4) << 9) + lane * 8;
      bf16x8 kb[4][4];
#pragma unroll
      for (int nt = 0; nt < 4; nt++)
#pragma unroll
        for (int dc = 0; dc < 4; dc++)
          kb[nt][dc] = *(const bf16x8*)(kp + (((size_t)nt * 32 + dc) << 9));

      floatx4 s[2][4] = {};
#pragma unroll
      for (int nt = 0; nt < 4; nt++)
#pragma unroll
        for (int dc = 0; dc < 4; dc++)
#pragma unroll
          for (int mt = 0; mt < 2; mt++)
            s[mt][nt] = __builtin_amdgcn_mfma_f32_16x16x32_bf16(qfr[mt][dc], kb[nt][dc], s[mt][nt], 0, 0, 0);

#pragma unroll
      for (int mt = 0; mt < 2; mt++)
#pragma unroll
        for (int nt = 0; nt < 4; nt++)
#pragma unroll
          for (int r = 0; r < 4; r++)
            Sf[wave][mt * 16 + quad * 4 + r][nt * 16 + l16] = s[mt][nt][r];
      __syncthreads();  // B0: all partials in LDS

      // issue V loads now; they stream under the softmax VALU work
      const short* vp = Vf + ((((size_t)b * 64 + wave * 8) * 64 + kt * 2) << 9) + lane * 8;
      bf16x8 vb[2][8];
#pragma unroll
      for (int nb = 0; nb < 8; nb++)
#pragma unroll
        for (int kc = 0; kc < 2; kc++)
          vb[kc][nb] = *(const bf16x8*)(vp + (((size_t)nb * 64 + kc) << 9));

      const int kvbase = kt * 64;
      floatx4 vsum = {};
#pragma unroll
      for (int w = 0; w < 8; w++)
        vsum += *(const floatx4*)&Sf[w][row][sub * 4];
      float sv[4], mx = -1e30f;
#pragma unroll
      for (int jj = 0; jj < 4; jj++) {
        float v = vsum[jj];
        if (kvbase + sub * 4 + jj > gr) v = -1e30f;  // causal mask
        sv[jj] = v;
        mx = fmaxf(mx, v);
      }
#pragma unroll
      for (int msk = 1; msk <= 8; msk <<= 1)
        mx = fmaxf(mx, __shfl_xor(mx, msk, 64));
      const float mn = fmaxf(m_i, mx);
      const float alpha = __expf(m_i - mn);
      m_i = mn;
      float ps = 0.0f;
      short4v pb4;
#pragma unroll
      for (int jj = 0; jj < 4; jj++) {
        float pe = __expf(sv[jj] - mn);
        ps += pe;
        pb4[jj] = f2bf(pe);
      }
      *(short4v*)&Pb[row][sub * 4] = pb4;
#pragma unroll
      for (int msk = 1; msk <= 8; msk <<= 1)
        ps += __shfl_xor(ps, msk, 64);
      l_i = l_i * alpha + ps;
      if (sub == 0) arow[row] = alpha;
      __syncthreads();  // B1: Pb + arow ready

      float al[2][4];
#pragma unroll
      for (int mt = 0; mt < 2; mt++)
#pragma unroll
        for (int r = 0; r < 4; r++) al[mt][r] = arow[mt * 16 + quad * 4 + r];
#pragma unroll
      for (int mt = 0; mt < 2; mt++)
#pragma unroll
        for (int nb = 0; nb < 8; nb++)
#pragma unroll
          for (int r = 0; r < 4; r++) O[mt][nb][r] *= al[mt][r];

#pragma unroll
      for (int kc = 0; kc < 2; kc++)
#pragma unroll
        for (int mt = 0; mt < 2; mt++) {
          bf16x8 pa = *(const bf16x8*)&Pb[mt * 16 + l16][kc * 32 + quad * 8];
#pragma unroll
          for (int nb = 0; nb < 8; nb++)
            O[mt][nb] = __builtin_amdgcn_mfma_f32_16x16x32_bf16(pa, vb[kc][nb], O[mt][nb], 0, 0, 0);
        }
    }  // kt

    if (sub == 0) lrow[row] = 1.0f / l_i;
    __syncthreads();
    float linv[2][4];
#pragma unroll
    for (int mt = 0; mt < 2; mt++)
#pragma unroll
      for (int r = 0; r < 4; r++) linv[mt][r] = lrow[mt * 16 + quad * 4 + r];
#pragma unroll
    for (int mt = 0; mt < 2; mt++)
#pragma unroll
      for (int nb = 0; nb < 8; nb++)
#pragma unroll
        for (int r = 0; r < 4; r++) {
          const int rr = j * 32 + mt * 16 + quad * 4 + r;
          const int cc = wave * 128 + nb * 16 + l16;
          out[((size_t)b * 2048 + rr) * 1024 + cc] = O[mt][nb][r] * linv[mt][r];
        }
  }  // pass
}

extern "C" void kernel_launch(void* const* d_in, const int* in_sizes, int n_in,
                              void* d_out, int out_size, void* d_ws, size_t ws_size,
                              hipStream_t stream) {
  const float* x  = (const float*)d_in[0];
  const float* Wq = (const float*)d_in[1];
  const float* bq = (const float*)d_in[2];
  const float* Wk = (const float*)d_in[3];
  const float* bk = (const float*)d_in[4];
  const float* Wv = (const float*)d_in[5];
  const float* bv = (const float*)d_in[6];
  float* out = (float*)d_out;

  char* ws = (char*)d_ws;
  short* Xb = (short*)(ws);                 // 16384x1024 bf16 = 33,554,432 B
  short* Wb = (short*)(ws + 33554432);      // 3x1024x1024 bf16 = 6,291,456 B
  short* Qf = (short*)(ws + 39845888);      // 33,554,432 B fragment-linear
  short* Kf = (short*)(ws + 73400320);      // 33,554,432 B fragment-linear
  short* Vf = (short*)(ws + 106954752);     // 33,554,432 B fragment-linear

  cvt_kernel<<<19456, 256, 0, stream>>>(x, Wq, Wk, Wv, Xb, Wb);
  qkv_gemm<<<dim3(768), 512, 0, stream>>>(Xb, Wb, bq, bk, bv, Qf, Kf, Vf);
  flash_attn<<<256, 512, 0, stream>>>(Qf, Kf, Vf, out);
}